// Round 10
// baseline (692.224 us; speedup 1.0000x reference)
//
#include <hip/hip_runtime.h>
#include <cstdint>
#include <cstddef>

typedef __bf16 bf16_t;
typedef float f32x4 __attribute__((ext_vector_type(4)));
typedef __bf16 bf16x8 __attribute__((ext_vector_type(8)));

// ---------------- problem constants ----------------
#define TOKENS      16384
#define IN_F        4096
#define OUT_F       4096
#define NACT        2048
#define MHALF       8192

// ---------------- workspace layout (bytes) ----------------
static constexpr size_t OFF_PERM  = 0;                      // 4096 * 4
static constexpr size_t OFF_ACT   = 16384;                  // 2048 * 4
static constexpr size_t OFF_OIP   = 24576;                  // 4096 * 4
static constexpr size_t OFF_OP    = 40960;                  // 4096 * 4
static constexpr size_t OFF_IPINV = 57344;                  // 4096 * 4
static constexpr size_t OFF_DHT   = 73728;                  // 128*128 * 2 (bf16)
static constexpr size_t OFF_TAB   = 106496;                 // 16384 * 4 cos table
static constexpr size_t OFF_T     = 172032;                 // 8 MB
static constexpr size_t OFF_AM    = OFF_T    + 8388608;     // 32 MB
static constexpr size_t OFF_WIN   = OFF_AM   + 33554432;    // 16 MB
static constexpr size_t OFF_WOUT  = OFF_WIN  + 16777216;    // 16 MB
// xa-half overlays T/Amat during main phase (r3-proven overlay)
static constexpr size_t OFF_XA_S  = OFF_T;                  // 32 MB
static constexpr size_t WS_SMALL  = OFF_WOUT + 16777216;    // ~91 MB

// ---------------- helpers ----------------
__device__ __forceinline__ void gload_lds16(const void* gsrc, void* ldsdst) {
    __builtin_amdgcn_global_load_lds(
        (__attribute__((address_space(1))) void*)(uintptr_t)gsrc,
        (__attribute__((address_space(3))) void*)(uint32_t)(uintptr_t)ldsdst,
        16, 0, 0);
}

__device__ __forceinline__ int is_i64_flag(const int* p) {
    int s = 0;
    #pragma unroll
    for (int i = 1; i < 64; i += 2) s |= p[i];
    return s == 0;
}

// ---------------- index normalization (int64-or-int32 -> int32) ----------------
__global__ void k_norm_idx(const int* __restrict__ perm_raw,
                           const int* __restrict__ act_raw,
                           const int* __restrict__ oip_raw,
                           int* __restrict__ perm, int* __restrict__ act,
                           int* __restrict__ oip) {
    int i = blockIdx.x * blockDim.x + threadIdx.x;
    int p64 = is_i64_flag(perm_raw);
    int a64 = is_i64_flag(act_raw);
    int o64 = is_i64_flag(oip_raw);
    if (i < 4096) perm[i] = p64 ? perm_raw[2*i] : perm_raw[i];
    if (i < 2048) act[i]  = a64 ? act_raw[2*i]  : act_raw[i];
    if (i < 4096) oip[i]  = o64 ? oip_raw[2*i]  : oip_raw[i];
}

__global__ void k_invert(const int* __restrict__ oip, const int* __restrict__ perm,
                         int* __restrict__ op, int* __restrict__ ipinv) {
    int j = blockIdx.x * 256 + threadIdx.x;
    if (j < 4096) {
        op[oip[j]]     = j;   // forward output perm
        ipinv[perm[j]] = j;   // inverse input perm
    }
}

// ---------------- cos table: tab[i] = cos(pi * i / 8192), i in [0,16384) ----------------
__global__ void k_costab(float* __restrict__ tab) {
    int i = blockIdx.x * 256 + threadIdx.x;    // 64 blocks
    tab[i] = cosf((float)i * 3.834951969e-4f);
}

// ---------------- DCT-128 transpose table, bf16: DhT[m][k] = Dh[k][m] ----------------
__global__ void k_dht(const float* __restrict__ tab, bf16_t* __restrict__ DhT) {
    int idx = blockIdx.x * 256 + threadIdx.x;   // 64 blocks
    int m = idx >> 7, k = idx & 127;
    unsigned ph = ((unsigned)(2*m + 1) * (unsigned)k) & 511u;   // period 4n = 512
    float v = 0.125f * tab[ph << 5];                            // cos(pi*ph/256)
    if (k == 0) v *= 0.70710678119f;
    DhT[m*128 + k] = (bf16_t)v;
}

// ---- WinT[c][r] = D4096[act[c], m] with m = ipinv[r]; table gather ----
__global__ void k_win(const int* __restrict__ ipinv, const int* __restrict__ act,
                      const float* __restrict__ tab, bf16_t* __restrict__ WinT) {
    int c = blockIdx.x;           // 2048 blocks
    int kk = act[c];
    float rowscale = 0.02209708691f * (kk == 0 ? 0.70710678119f : 1.0f); // sqrt(2/4096)
    for (int r = threadIdx.x; r < 4096; r += 256) {
        int m = ipinv[r];
        unsigned ph = ((unsigned)(2*m + 1) * (unsigned)kk) & 16383u;     // period 4n = 16384
        WinT[(size_t)c * 4096 + r] = (bf16_t)(rowscale * tab[ph]);
    }
}

// ---------------- T[r,j,q,k,u] = sum_s G2[r,j,q,s] * G3[s,k,u] ----------------
__global__ __launch_bounds__(256) void k_build_T(const float* __restrict__ G2,
                                                 const float* __restrict__ G3,
                                                 float* __restrict__ T) {
    __shared__ alignas(16) float g3s[64*8*16];   // 32 KB
    __shared__ float g2t[64*16];                 // [s][q], 4 KB
    int rj = blockIdx.x;                          // 1024 blocks: r*16 + j
    int r = rj >> 4, j = rj & 15;
    for (int idx = threadIdx.x; idx < 8192; idx += 256) g3s[idx] = G3[idx];
    for (int idx = threadIdx.x; idx < 1024; idx += 256) {
        int s = idx >> 4, q = idx & 15;
        g2t[idx] = G2[((size_t)((r*16 + j)*16 + q))*64 + s];
    }
    __syncthreads();
    int q = threadIdx.x >> 4, u = threadIdx.x & 15;
    float acc[8] = {0.f};
    for (int s = 0; s < 64; ++s) {
        float g2 = g2t[s*16 + q];
        #pragma unroll
        for (int k = 0; k < 8; ++k) acc[k] += g2 * g3s[(s*8 + k)*16 + u];
    }
    size_t base = ((size_t)((r*16 + j)*16 + q) * 8) * 16 + u;
    #pragma unroll
    for (int k = 0; k < 8; ++k) T[base + k*16] = acc[k];
}

// ---------------- A[cin][cout] = sum_r G1[i,p,r] * T[r,j,q,k,u] ----------------
__global__ __launch_bounds__(256) void k_build_A(const float* __restrict__ G1,
                                                 const float* __restrict__ T,
                                                 float* __restrict__ Amat) {
    __shared__ alignas(16) float Tl[64*16*16];   // [r][q][slot-swizzled], 64 KB
    __shared__ float g1t[64*16];                 // [r][p], 4 KB
    int cin = blockIdx.x;                         // 2048 blocks
    int i = cin >> 7, j = (cin >> 3) & 15, k = cin & 7;
    #pragma unroll
    for (int it = 0; it < 16; ++it) {
        int idx = it*256 + threadIdx.x;          // f32x4 index, 0..4095
        int slot = idx & 3, q = (idx >> 2) & 15, r = idx >> 6;
        f32x4 tv = *(const f32x4*)&T[(((((size_t)r*16 + j)*16 + q)*8) + k)*16 + slot*4];
        *(f32x4*)&Tl[(r*16 + q)*16 + ((slot ^ ((q >> 1) & 3)) << 2)] = tv;
    }
    for (int idx = threadIdx.x; idx < 1024; idx += 256) {
        int r = idx >> 4, p = idx & 15;
        g1t[idx] = G1[(i*16 + p)*64 + r];
    }
    __syncthreads();
    int p = threadIdx.x >> 4, q = threadIdx.x & 15;
    int qs = (q >> 1) & 3;
    f32x4 acc4[4];
    #pragma unroll
    for (int a = 0; a < 4; ++a) acc4[a] = (f32x4){0.f, 0.f, 0.f, 0.f};
    for (int r = 0; r < 64; ++r) {
        float g = g1t[r*16 + p];
        #pragma unroll
        for (int ub = 0; ub < 4; ++ub) {         // static acc index, runtime address
            f32x4 tv = *(const f32x4*)&Tl[(r*16 + q)*16 + ((ub ^ qs) << 2)];
            acc4[ub] += tv * g;
        }
    }
    size_t base = (size_t)cin * 4096 + p*256 + q*16;
    #pragma unroll
    for (int ub = 0; ub < 4; ++ub) *(f32x4*)&Amat[base + ub*4] = acc4[ub];
}

// ---- WoutT via MFMA: Out[128c][128m] = A_blk[c][k](bf16) x DhT[m][k](bf16)^T ----
__global__ __launch_bounds__(256) void k_wout_mfma(const float* __restrict__ Amat,
                                                   const bf16_t* __restrict__ DhT,
                                                   const int* __restrict__ op,
                                                   bf16_t* __restrict__ WoutT) {
    __shared__ alignas(16) bf16_t Al[128*128];   // 32 KB  [c][k]
    __shared__ alignas(16) bf16_t Bl[128*128];   // 32 KB  [m][k]
    const int h  = blockIdx.x;
    const int c0 = blockIdx.y * 128;
    const int t = threadIdx.x, lane = t & 63, wv = t >> 6;
    const int wm = wv >> 1, wn = wv & 1;
    const int frow = lane & 15, kg = lane >> 4;

    #pragma unroll
    for (int it = 0; it < 8; ++it) {
        int idx = it*256 + t;                    // 0..2047
        int row = idx >> 4, slot = idx & 15;
        int dst = row*256 + ((slot*16) ^ ((row & 7) << 4));   // byte offset
        const float* s = Amat + (size_t)(c0 + row)*4096 + h*128 + slot*8;
        f32x4 v0 = *(const f32x4*)s;
        f32x4 v1 = *(const f32x4*)(s + 4);
        bf16x8 av;
        av[0]=(bf16_t)v0[0]; av[1]=(bf16_t)v0[1]; av[2]=(bf16_t)v0[2]; av[3]=(bf16_t)v0[3];
        av[4]=(bf16_t)v1[0]; av[5]=(bf16_t)v1[1]; av[6]=(bf16_t)v1[2]; av[7]=(bf16_t)v1[3];
        *(bf16x8*)((char*)Al + dst) = av;
        bf16x8 dv = *(const bf16x8*)(DhT + row*128 + slot*8);
        *(bf16x8*)((char*)Bl + dst) = dv;
    }
    __syncthreads();

    f32x4 acc[4][4];
    #pragma unroll
    for (int a = 0; a < 4; ++a)
        #pragma unroll
        for (int b = 0; b < 4; ++b) acc[a][b] = (f32x4){0.f, 0.f, 0.f, 0.f};

    #pragma unroll
    for (int ks = 0; ks < 4; ++ks) {
        bf16x8 af[4], bfr[4];
        #pragma unroll
        for (int mt = 0; mt < 4; ++mt) {
            int r = wm*64 + mt*16 + frow;
            af[mt] = *(const bf16x8*)((char*)Al + r*256 + ((ks*64 + kg*16) ^ ((r & 7) << 4)));
        }
        #pragma unroll
        for (int nt = 0; nt < 4; ++nt) {
            int r = wn*64 + nt*16 + frow;
            bfr[nt] = *(const bf16x8*)((char*)Bl + r*256 + ((ks*64 + kg*16) ^ ((r & 7) << 4)));
        }
        #pragma unroll
        for (int mt = 0; mt < 4; ++mt)
            #pragma unroll
            for (int nt = 0; nt < 4; ++nt)
                acc[mt][nt] = __builtin_amdgcn_mfma_f32_16x16x32_bf16(
                    af[mt], bfr[nt], acc[mt][nt], 0, 0, 0);
    }

    const int ccol  = lane & 15;
    const int crow0 = (lane >> 4) * 4;
    #pragma unroll
    for (int nt = 0; nt < 4; ++nt) {
        const int m = wn*64 + nt*16 + ccol;
        const int jj = op[h*128 + m];
        #pragma unroll
        for (int mt = 0; mt < 4; ++mt) {
            #pragma unroll
            for (int i = 0; i < 4; ++i) {
                const int c = c0 + wm*64 + mt*16 + crow0 + i;
                WoutT[(size_t)jj * 2048 + c] = (bf16_t)acc[mt][nt][i];
            }
        }
    }
}

// ---------------- shared GEMM helpers ----------------
__device__ __forceinline__ bf16x8 read_frag(const bf16_t* lds, int row, int slot) {
    return *(const bf16x8*)(lds + (((row << 3) + (slot ^ (row & 7))) << 3));
}

// ============ GEMM2: 256x256 8-wave, bf16 A via gload_lds, single barrier/iter ============
__global__ __launch_bounds__(512, 2)
void gemm2s(const bf16_t* __restrict__ A, const bf16_t* __restrict__ Bt,
            float* __restrict__ Cp, const float* __restrict__ bias,
            int N, int K, int nbn) {
    __shared__ alignas(16) bf16_t lds[2][2][256*64];   // 128 KB

    const int tid  = threadIdx.x;
    const int lane = tid & 63;
    const int wid  = tid >> 6;
    const int wm   = wid >> 2;
    const int wn   = wid & 3;
    const int frow = lane & 15;
    const int kg   = lane >> 4;

    const int nwg = gridDim.x;
    const int cpx = nwg >> 3;
    const int swz = (blockIdx.x & 7) * cpx + (blockIdx.x >> 3);
    const int m0  = (swz / nbn) * 256;
    const int n0  = (swz % nbn) * 256;

    const bf16_t* gA = A  + (size_t)m0 * K;
    const bf16_t* gB = Bt + (size_t)n0 * K;

    auto stage = [&](int kt) {
        bf16_t* dA = &lds[kt & 1][0][0];
        bf16_t* dB = &lds[kt & 1][1][0];
        #pragma unroll
        for (int i = 0; i < 4; ++i) {
            int q = i*512 + tid, row = q >> 3, s = q & 7;
            gload_lds16(gA + (size_t)row*K + kt*64 + ((s ^ (row & 7)) << 3), dA + q*8);
        }
        #pragma unroll
        for (int i = 0; i < 4; ++i) {
            int q = i*512 + tid, row = q >> 3, s = q & 7;
            gload_lds16(gB + (size_t)row*K + kt*64 + ((s ^ (row & 7)) << 3), dB + q*8);
        }
    };

    f32x4 acc[8][4];
    #pragma unroll
    for (int a = 0; a < 8; ++a)
        #pragma unroll
        for (int b = 0; b < 4; ++b) acc[a][b] = (f32x4){0.f, 0.f, 0.f, 0.f};

    const int NT = K >> 6;
    stage(0);
    asm volatile("s_waitcnt vmcnt(0)" ::: "memory");
    __builtin_amdgcn_s_barrier();

    for (int t = 0; t < NT; ++t) {
        const int cur = t & 1;
        if (t + 1 < NT) stage(t + 1);

        const bf16_t* lA = &lds[cur][0][0];
        const bf16_t* lB = &lds[cur][1][0];
        __builtin_amdgcn_s_setprio(1);
        #pragma unroll
        for (int ks = 0; ks < 2; ++ks) {
            bf16x8 bfr[4];
            #pragma unroll
            for (int nt = 0; nt < 4; ++nt)
                bfr[nt] = read_frag(lB, wn*64 + nt*16 + frow, ks*4 + kg);
            #pragma unroll
            for (int mt = 0; mt < 8; ++mt) {
                bf16x8 af = read_frag(lA, wm*128 + mt*16 + frow, ks*4 + kg);
                #pragma unroll
                for (int nt = 0; nt < 4; ++nt)
                    acc[mt][nt] = __builtin_amdgcn_mfma_f32_16x16x32_bf16(
                        af, bfr[nt], acc[mt][nt], 0, 0, 0);
            }
        }
        __builtin_amdgcn_s_setprio(0);

        if (t + 1 < NT) {
            asm volatile("s_waitcnt vmcnt(0)" ::: "memory");   // free: issued pre-compute
            __builtin_amdgcn_s_barrier();                      // publish + WAR fence
        }
    }

    const int ccol  = lane & 15;
    const int crow0 = (lane >> 4) * 4;
    #pragma unroll
    for (int nt = 0; nt < 4; ++nt) {
        const int col = n0 + wn*64 + nt*16 + ccol;
        const float bv = bias[col];
        #pragma unroll
        for (int mt = 0; mt < 8; ++mt) {
            const int row = m0 + wm*128 + mt*16 + crow0;
            #pragma unroll
            for (int i = 0; i < 4; ++i)
                Cp[(size_t)(row + i)*N + col] = acc[mt][nt][i] + bv;
        }
    }
}

// ============ GEMM1 fused-cvt v2: cvt+ds_write hidden between compute halves ============
// Iter t: issue loadA(t+1) (8x dwordx4 -> regs) then stageB(t+1) (4x gload_lds);
//   compute ks=0 on dbuf[cur]; writeA(t+1) -> dbuf[cur^1] (compiler auto-waits the
//   A loads only; B's 4 gload_lds stay outstanding; WAR safe: dbuf[cur^1] A-readers
//   finished before end-of-(t-1) barrier); compute ks=1 (~1300cy drains ds_writes);
//   vmcnt(0) (B) + lgkmcnt(0) (ds_writes) + barrier -- both waits near-free.
__global__ __launch_bounds__(512, 2)
void gemmf(const float* __restrict__ A, const bf16_t* __restrict__ Bt,
           bf16_t* __restrict__ Cp, int N, int K, int nbn) {
    __shared__ alignas(16) bf16_t lds[2][2][256*64];   // 128 KB

    const int tid  = threadIdx.x;
    const int lane = tid & 63;
    const int wid  = tid >> 6;
    const int wm   = wid >> 2;
    const int wn   = wid & 3;
    const int frow = lane & 15;
    const int kg   = lane >> 4;

    const int nwg = gridDim.x;
    const int cpx = nwg >> 3;
    const int swz = (blockIdx.x & 7) * cpx + (blockIdx.x >> 3);
    const int m0  = (swz / nbn) * 256;
    const int n0  = (swz % nbn) * 256;

    const float*  gA = A  + (size_t)m0 * K;
    const bf16_t* gB = Bt + (size_t)n0 * K;

    // A granules: 2048 = 256 rows x 8 slots of bf16x8; 4 per thread.
    f32x4 ar[4][2];
    auto loadA = [&](int kt) {
        #pragma unroll
        for (int i = 0; i < 4; ++i) {
            int g = i*512 + tid, row = g >> 3, sl = g & 7;
            const float* p = gA + (size_t)row*K + kt*64 + sl*8;
            ar[i][0] = *(const f32x4*)p;
            ar[i][1] = *(const f32x4*)(p + 4);
        }
    };
    auto writeA = [&](int kt) {
        bf16_t* dA = &lds[kt & 1][0][0];
        #pragma unroll
        for (int i = 0; i < 4; ++i) {
            int g = i*512 + tid, row = g >> 3, sl = g & 7;
            bf16x8 v;
            v[0]=(bf16_t)ar[i][0][0]; v[1]=(bf16_t)ar[i][0][1];
            v[2]=(bf16_t)ar[i][0][2]; v[3]=(bf16_t)ar[i][0][3];
            v[4]=(bf16_t)ar[i][1][0]; v[5]=(bf16_t)ar[i][1][1];
            v[6]=(bf16_t)ar[i][1][2]; v[7]=(bf16_t)ar[i][1][3];
            *(bf16x8*)(dA + (((row << 3) + (sl ^ (row & 7))) << 3)) = v;
        }
    };
    auto stageB = [&](int kt) {
        bf16_t* dB = &lds[kt & 1][1][0];
        #pragma unroll
        for (int i = 0; i < 4; ++i) {
            int q = i*512 + tid, row = q >> 3, s = q & 7;
            gload_lds16(gB + (size_t)row*K + kt*64 + ((s ^ (row & 7)) << 3), dB + q*8);
        }
    };

    f32x4 acc[8][4];
    #pragma unroll
    for (int a = 0; a < 8; ++a)
        #pragma unroll
        for (int b = 0; b < 4; ++b) acc[a][b] = (f32x4){0.f, 0.f, 0.f, 0.f};

    const int NT = K >> 6;
    // prologue: tile 0 fully staged (latency exposed once)
    loadA(0); stageB(0);
    asm volatile("s_waitcnt vmcnt(0)" ::: "memory");
    writeA(0);
    asm volatile("s_waitcnt lgkmcnt(0)" ::: "memory");
    __builtin_amdgcn_s_barrier();

    for (int t = 0; t < NT; ++t) {
        const int cur = t & 1;
        if (t + 1 < NT) { loadA(t + 1); stageB(t + 1); }

        const bf16_t* lA = &lds[cur][0][0];
        const bf16_t* lB = &lds[cur][1][0];

        // ---- compute half ks=0 ----
        __builtin_amdgcn_s_setprio(1);
        {
            bf16x8 bfr[4];
            #pragma unroll
            for (int nt = 0; nt < 4; ++nt)
                bfr[nt] = read_frag(lB, wn*64 + nt*16 + frow, kg);
            #pragma unroll
            for (int mt = 0; mt < 8; ++mt) {
                bf16x8 af = read_frag(lA, wm*128 + mt*16 + frow, kg);
                #pragma unroll
                for (int nt = 0; nt < 4; ++nt)
                    acc[mt][nt] = __builtin_amdgcn_mfma_f32_16x16x32_bf16(
                        af, bfr[nt], acc[mt][nt], 0, 0, 0);
            }
        }
        __builtin_amdgcn_s_setprio(0);

        // ---- hidden cvt+write of A(t+1) into dbuf[cur^1] ----
        if (t + 1 < NT) writeA(t + 1);

        // ---- compute half ks=1 (drains the ds_writes underneath) ----
        __builtin_amdgcn_s_setprio(1);
        {
            bf16x8 bfr[4];
            #pragma unroll
            for (int nt = 0; nt < 4; ++nt)
                bfr[nt] = read_frag(lB, wn*64 + nt*16 + frow, 4 + kg);
            #pragma unroll
            for (int mt = 0; mt < 8; ++mt) {
                bf16x8 af = read_frag(lA, wm*128 + mt*16 + frow, 4 + kg);
                #pragma unroll
                for (int nt = 0; nt < 4; ++nt)
                    acc[mt][nt] = __builtin_amdgcn_mfma_f32_16x16x32_bf16(
                        af, bfr[nt], acc[mt][nt], 0, 0, 0);
            }
        }
        __builtin_amdgcn_s_setprio(0);

        if (t + 1 < NT) {
            asm volatile("s_waitcnt vmcnt(0) lgkmcnt(0)" ::: "memory");  // both near-free
            __builtin_amdgcn_s_barrier();                                // publish + WAR
        }
    }

    const int ccol  = lane & 15;
    const int crow0 = (lane >> 4) * 4;
    #pragma unroll
    for (int nt = 0; nt < 4; ++nt) {
        const int col = n0 + wn*64 + nt*16 + ccol;
        #pragma unroll
        for (int mt = 0; mt < 8; ++mt) {
            const int row = m0 + wm*128 + mt*16 + crow0;
            #pragma unroll
            for (int i = 0; i < 4; ++i)
                Cp[(size_t)(row + i)*N + col] = (bf16_t)acc[mt][nt][i];
        }
    }
}

// ---------------- launcher ----------------
extern "C" void kernel_launch(void* const* d_in, const int* in_sizes, int n_in,
                              void* d_out, int out_size, void* d_ws, size_t ws_size,
                              hipStream_t stream) {
    (void)in_sizes; (void)n_in; (void)out_size;
    const float* x    = (const float*)d_in[0];
    const float* G1   = (const float*)d_in[1];
    const float* G2   = (const float*)d_in[2];
    const float* G3   = (const float*)d_in[3];
    const float* bias = (const float*)d_in[4];
    const int* perm_raw = (const int*)d_in[5];
    const int* act_raw  = (const int*)d_in[6];
    const int* oip_raw  = (const int*)d_in[7];

    if (ws_size < WS_SMALL) return;

    char* ws = (char*)d_ws;
    int*    perm  = (int*)   (ws + OFF_PERM);
    int*    act   = (int*)   (ws + OFF_ACT);
    int*    oip   = (int*)   (ws + OFF_OIP);
    int*    op    = (int*)   (ws + OFF_OP);
    int*    ipinv = (int*)   (ws + OFF_IPINV);
    bf16_t* DhT   = (bf16_t*)(ws + OFF_DHT);
    float*  tab   = (float*) (ws + OFF_TAB);
    float*  T     = (float*) (ws + OFF_T);
    float*  Amat  = (float*) (ws + OFF_AM);
    bf16_t* WinT  = (bf16_t*)(ws + OFF_WIN);
    bf16_t* WoutT = (bf16_t*)(ws + OFF_WOUT);
    bf16_t* xa    = (bf16_t*)(ws + OFF_XA_S);   // overlays dead T/Amat during main

    // ---- prep (weights) ----
    k_norm_idx<<<16, 256, 0, stream>>>(perm_raw, act_raw, oip_raw, perm, act, oip);
    k_invert  <<<16, 256, 0, stream>>>(oip, perm, op, ipinv);
    k_costab  <<<64, 256, 0, stream>>>(tab);
    k_dht     <<<64, 256, 0, stream>>>(tab, DhT);
    k_win     <<<2048, 256, 0, stream>>>(ipinv, act, tab, WinT);
    k_build_T <<<1024, 256, 0, stream>>>(G2, G3, T);
    k_build_A <<<2048, 256, 0, stream>>>(G1, T, Amat);
    k_wout_mfma<<<dim3(32, 16), 256, 0, stream>>>(Amat, DhT, op, WoutT);

    // ---- main: two M-halves; GEMM1 reads x (fp32) directly, no cvt kernel ----
    for (int h = 0; h < 2; ++h) {
        const float* xh = x + (size_t)h * MHALF * IN_F;
        float* outh = (float*)d_out + (size_t)h * MHALF * OUT_F;
        // GEMM1: xa[8192][2048] = cvt_bf16(xh) @ WinT^T   (32 x 8 = 256 wgs)
        gemmf<<<256, 512, 0, stream>>>(xh, WinT, xa, NACT, IN_F, NACT/256);
        // GEMM2: out[8192][4096] = xa @ WoutT^T + bias    (32 x 16 = 512 wgs)
        gemm2s<<<512, 512, 0, stream>>>(xa, WoutT, outh, bias, OUT_F, NACT, OUT_F/256);
    }
}

// Round 11
// 668.200 us; speedup vs baseline: 1.0360x; 1.0360x over previous
//
#include <hip/hip_runtime.h>
#include <cstdint>
#include <cstddef>

typedef __bf16 bf16_t;
typedef float f32x4 __attribute__((ext_vector_type(4)));
typedef __bf16 bf16x8 __attribute__((ext_vector_type(8)));

// ---------------- problem constants ----------------
#define TOKENS      16384
#define IN_F        4096
#define OUT_F       4096
#define NACT        2048
#define MHALF       8192

// ---------------- workspace layout (bytes) ----------------
static constexpr size_t OFF_PERM  = 0;                      // 4096 * 4
static constexpr size_t OFF_ACT   = 16384;                  // 2048 * 4
static constexpr size_t OFF_OIP   = 24576;                  // 4096 * 4
static constexpr size_t OFF_OP    = 40960;                  // 4096 * 4
static constexpr size_t OFF_IPINV = 57344;                  // 4096 * 4
static constexpr size_t OFF_DHT   = 73728;                  // 128*128 * 2 (bf16)
static constexpr size_t OFF_TAB   = 106496;                 // 16384 * 4 cos table
static constexpr size_t OFF_T     = 172032;                 // 8 MB
static constexpr size_t OFF_AM    = OFF_T    + 8388608;     // 32 MB
static constexpr size_t OFF_WIN   = OFF_AM   + 33554432;    // 16 MB
static constexpr size_t OFF_WOUT  = OFF_WIN  + 16777216;    // 16 MB
static constexpr size_t OFF_XB    = OFF_WOUT + 16777216;    // 64 MB (x half, bf16)
static constexpr size_t WS_SMALL  = OFF_XB   + 67108864;    // 142,778,368 B
// xa-half (32 MB) overlays dead T+Amat region during main phase
static constexpr size_t OFF_XA_S  = OFF_T;

// ---------------- helpers ----------------
__device__ __forceinline__ void gload_lds16(const void* gsrc, void* ldsdst) {
    __builtin_amdgcn_global_load_lds(
        (__attribute__((address_space(1))) void*)(uintptr_t)gsrc,
        (__attribute__((address_space(3))) void*)(uint32_t)(uintptr_t)ldsdst,
        16, 0, 0);
}

__device__ __forceinline__ int is_i64_flag(const int* p) {
    int s = 0;
    #pragma unroll
    for (int i = 1; i < 64; i += 2) s |= p[i];
    return s == 0;
}

// ---------------- index normalization (int64-or-int32 -> int32) ----------------
__global__ void k_norm_idx(const int* __restrict__ perm_raw,
                           const int* __restrict__ act_raw,
                           const int* __restrict__ oip_raw,
                           int* __restrict__ perm, int* __restrict__ act,
                           int* __restrict__ oip) {
    int i = blockIdx.x * blockDim.x + threadIdx.x;
    int p64 = is_i64_flag(perm_raw);
    int a64 = is_i64_flag(act_raw);
    int o64 = is_i64_flag(oip_raw);
    if (i < 4096) perm[i] = p64 ? perm_raw[2*i] : perm_raw[i];
    if (i < 2048) act[i]  = a64 ? act_raw[2*i]  : act_raw[i];
    if (i < 4096) oip[i]  = o64 ? oip_raw[2*i]  : oip_raw[i];
}

__global__ void k_invert(const int* __restrict__ oip, const int* __restrict__ perm,
                         int* __restrict__ op, int* __restrict__ ipinv) {
    int j = blockIdx.x * 256 + threadIdx.x;
    if (j < 4096) {
        op[oip[j]]     = j;   // forward output perm
        ipinv[perm[j]] = j;   // inverse input perm
    }
}

// ---------------- cos table: tab[i] = cos(pi * i / 8192), i in [0,16384) ----------------
__global__ void k_costab(float* __restrict__ tab) {
    int i = blockIdx.x * 256 + threadIdx.x;    // 64 blocks
    tab[i] = cosf((float)i * 3.834951969e-4f);
}

// ---------------- DCT-128 transpose table, bf16: DhT[m][k] = Dh[k][m] ----------------
__global__ void k_dht(const float* __restrict__ tab, bf16_t* __restrict__ DhT) {
    int idx = blockIdx.x * 256 + threadIdx.x;   // 64 blocks
    int m = idx >> 7, k = idx & 127;
    unsigned ph = ((unsigned)(2*m + 1) * (unsigned)k) & 511u;   // period 4n = 512
    float v = 0.125f * tab[ph << 5];                            // cos(pi*ph/256)
    if (k == 0) v *= 0.70710678119f;
    DhT[m*128 + k] = (bf16_t)v;
}

// ---- WinT[c][r] = D4096[act[c], m] with m = ipinv[r]; table gather ----
__global__ void k_win(const int* __restrict__ ipinv, const int* __restrict__ act,
                      const float* __restrict__ tab, bf16_t* __restrict__ WinT) {
    int c = blockIdx.x;           // 2048 blocks
    int kk = act[c];
    float rowscale = 0.02209708691f * (kk == 0 ? 0.70710678119f : 1.0f); // sqrt(2/4096)
    for (int r = threadIdx.x; r < 4096; r += 256) {
        int m = ipinv[r];
        unsigned ph = ((unsigned)(2*m + 1) * (unsigned)kk) & 16383u;     // period 4n = 16384
        WinT[(size_t)c * 4096 + r] = (bf16_t)(rowscale * tab[ph]);
    }
}

// ---------------- T[r,j,q,k,u] = sum_s G2[r,j,q,s] * G3[s,k,u] ----------------
__global__ __launch_bounds__(256) void k_build_T(const float* __restrict__ G2,
                                                 const float* __restrict__ G3,
                                                 float* __restrict__ T) {
    __shared__ alignas(16) float g3s[64*8*16];   // 32 KB
    __shared__ float g2t[64*16];                 // [s][q], 4 KB
    int rj = blockIdx.x;                          // 1024 blocks: r*16 + j
    int r = rj >> 4, j = rj & 15;
    for (int idx = threadIdx.x; idx < 8192; idx += 256) g3s[idx] = G3[idx];
    for (int idx = threadIdx.x; idx < 1024; idx += 256) {
        int s = idx >> 4, q = idx & 15;
        g2t[idx] = G2[((size_t)((r*16 + j)*16 + q))*64 + s];
    }
    __syncthreads();
    int q = threadIdx.x >> 4, u = threadIdx.x & 15;
    float acc[8] = {0.f};
    for (int s = 0; s < 64; ++s) {
        float g2 = g2t[s*16 + q];
        #pragma unroll
        for (int k = 0; k < 8; ++k) acc[k] += g2 * g3s[(s*8 + k)*16 + u];
    }
    size_t base = ((size_t)((r*16 + j)*16 + q) * 8) * 16 + u;
    #pragma unroll
    for (int k = 0; k < 8; ++k) T[base + k*16] = acc[k];
}

// ---------------- A[cin][cout] = sum_r G1[i,p,r] * T[r,j,q,k,u] ----------------
__global__ __launch_bounds__(256) void k_build_A(const float* __restrict__ G1,
                                                 const float* __restrict__ T,
                                                 float* __restrict__ Amat) {
    __shared__ alignas(16) float Tl[64*16*16];   // [r][q][slot-swizzled], 64 KB
    __shared__ float g1t[64*16];                 // [r][p], 4 KB
    int cin = blockIdx.x;                         // 2048 blocks
    int i = cin >> 7, j = (cin >> 3) & 15, k = cin & 7;
    #pragma unroll
    for (int it = 0; it < 16; ++it) {
        int idx = it*256 + threadIdx.x;          // f32x4 index, 0..4095
        int slot = idx & 3, q = (idx >> 2) & 15, r = idx >> 6;
        f32x4 tv = *(const f32x4*)&T[(((((size_t)r*16 + j)*16 + q)*8) + k)*16 + slot*4];
        *(f32x4*)&Tl[(r*16 + q)*16 + ((slot ^ ((q >> 1) & 3)) << 2)] = tv;
    }
    for (int idx = threadIdx.x; idx < 1024; idx += 256) {
        int r = idx >> 4, p = idx & 15;
        g1t[idx] = G1[(i*16 + p)*64 + r];
    }
    __syncthreads();
    int p = threadIdx.x >> 4, q = threadIdx.x & 15;
    int qs = (q >> 1) & 3;
    f32x4 acc4[4];
    #pragma unroll
    for (int a = 0; a < 4; ++a) acc4[a] = (f32x4){0.f, 0.f, 0.f, 0.f};
    for (int r = 0; r < 64; ++r) {
        float g = g1t[r*16 + p];
        #pragma unroll
        for (int ub = 0; ub < 4; ++ub) {         // static acc index, runtime address
            f32x4 tv = *(const f32x4*)&Tl[(r*16 + q)*16 + ((ub ^ qs) << 2)];
            acc4[ub] += tv * g;
        }
    }
    size_t base = (size_t)cin * 4096 + p*256 + q*16;
    #pragma unroll
    for (int ub = 0; ub < 4; ++ub) *(f32x4*)&Amat[base + ub*4] = acc4[ub];
}

// ---- WoutT via MFMA: Out[128c][128m] = A_blk[c][k](bf16) x DhT[m][k](bf16)^T ----
__global__ __launch_bounds__(256) void k_wout_mfma(const float* __restrict__ Amat,
                                                   const bf16_t* __restrict__ DhT,
                                                   const int* __restrict__ op,
                                                   bf16_t* __restrict__ WoutT) {
    __shared__ alignas(16) bf16_t Al[128*128];   // 32 KB  [c][k]
    __shared__ alignas(16) bf16_t Bl[128*128];   // 32 KB  [m][k]
    const int h  = blockIdx.x;
    const int c0 = blockIdx.y * 128;
    const int t = threadIdx.x, lane = t & 63, wv = t >> 6;
    const int wm = wv >> 1, wn = wv & 1;
    const int frow = lane & 15, kg = lane >> 4;

    #pragma unroll
    for (int it = 0; it < 8; ++it) {
        int idx = it*256 + t;                    // 0..2047
        int row = idx >> 4, slot = idx & 15;
        int dst = row*256 + ((slot*16) ^ ((row & 7) << 4));   // byte offset
        const float* s = Amat + (size_t)(c0 + row)*4096 + h*128 + slot*8;
        f32x4 v0 = *(const f32x4*)s;
        f32x4 v1 = *(const f32x4*)(s + 4);
        bf16x8 av;
        av[0]=(bf16_t)v0[0]; av[1]=(bf16_t)v0[1]; av[2]=(bf16_t)v0[2]; av[3]=(bf16_t)v0[3];
        av[4]=(bf16_t)v1[0]; av[5]=(bf16_t)v1[1]; av[6]=(bf16_t)v1[2]; av[7]=(bf16_t)v1[3];
        *(bf16x8*)((char*)Al + dst) = av;
        bf16x8 dv = *(const bf16x8*)(DhT + row*128 + slot*8);
        *(bf16x8*)((char*)Bl + dst) = dv;
    }
    __syncthreads();

    f32x4 acc[4][4];
    #pragma unroll
    for (int a = 0; a < 4; ++a)
        #pragma unroll
        for (int b = 0; b < 4; ++b) acc[a][b] = (f32x4){0.f, 0.f, 0.f, 0.f};

    #pragma unroll
    for (int ks = 0; ks < 4; ++ks) {
        bf16x8 af[4], bfr[4];
        #pragma unroll
        for (int mt = 0; mt < 4; ++mt) {
            int r = wm*64 + mt*16 + frow;
            af[mt] = *(const bf16x8*)((char*)Al + r*256 + ((ks*64 + kg*16) ^ ((r & 7) << 4)));
        }
        #pragma unroll
        for (int nt = 0; nt < 4; ++nt) {
            int r = wn*64 + nt*16 + frow;
            bfr[nt] = *(const bf16x8*)((char*)Bl + r*256 + ((ks*64 + kg*16) ^ ((r & 7) << 4)));
        }
        #pragma unroll
        for (int mt = 0; mt < 4; ++mt)
            #pragma unroll
            for (int nt = 0; nt < 4; ++nt)
                acc[mt][nt] = __builtin_amdgcn_mfma_f32_16x16x32_bf16(
                    af[mt], bfr[nt], acc[mt][nt], 0, 0, 0);
    }

    const int ccol  = lane & 15;
    const int crow0 = (lane >> 4) * 4;
    #pragma unroll
    for (int nt = 0; nt < 4; ++nt) {
        const int m = wn*64 + nt*16 + ccol;
        const int jj = op[h*128 + m];
        #pragma unroll
        for (int mt = 0; mt < 4; ++mt) {
            #pragma unroll
            for (int i = 0; i < 4; ++i) {
                const int c = c0 + wm*64 + mt*16 + crow0 + i;
                WoutT[(size_t)jj * 2048 + c] = (bf16_t)acc[mt][nt][i];
            }
        }
    }
}

// ---------------- fp32 -> bf16 conversion (one M-half of x) ----------------
__global__ void k_cvt(const float* __restrict__ x, bf16_t* __restrict__ xb) {
    size_t i = ((size_t)blockIdx.x * 256 + threadIdx.x) * 8;   // 16384 blocks
    f32x4 v0 = *(const f32x4*)(x + i);
    f32x4 v1 = *(const f32x4*)(x + i + 4);
    bf16x8 b;
    b[0]=(bf16_t)v0[0]; b[1]=(bf16_t)v0[1]; b[2]=(bf16_t)v0[2]; b[3]=(bf16_t)v0[3];
    b[4]=(bf16_t)v1[0]; b[5]=(bf16_t)v1[1]; b[6]=(bf16_t)v1[2]; b[7]=(bf16_t)v1[3];
    *(bf16x8*)(xb + i) = b;
}

// ---------------- shared GEMM helpers ----------------
__device__ __forceinline__ bf16x8 read_frag(const bf16_t* lds, int row, int slot) {
    return *(const bf16x8*)(lds + (((row << 3) + (slot ^ (row & 7))) << 3));
}

// ====== 256x256 8-wave GEMM, single barrier/iter (measured 4310 cy/tile, r9) ======
// Ledger: stage(t+1) issued before compute(t); vmcnt(0) after compute (cover = full
// compute region ~2900cy >= 900cy HBM, drain near-free); ONE end-of-iter barrier is
// both publish (drain precedes it) and WAR fence (reads consumed by MFMAs before it).
template<int OUTF>   // 0 -> bf16 out, 1 -> f32 out + bias
__global__ __launch_bounds__(512, 2)
void gemm2s(const bf16_t* __restrict__ A, const bf16_t* __restrict__ Bt,
            void* __restrict__ Cp, const float* __restrict__ bias,
            int N, int K, int nbn) {
    __shared__ alignas(16) bf16_t lds[2][2][256*64];   // 128 KB

    const int tid  = threadIdx.x;
    const int lane = tid & 63;
    const int wid  = tid >> 6;
    const int wm   = wid >> 2;
    const int wn   = wid & 3;
    const int frow = lane & 15;
    const int kg   = lane >> 4;

    const int nwg = gridDim.x;
    const int cpx = nwg >> 3;
    const int swz = (blockIdx.x & 7) * cpx + (blockIdx.x >> 3);
    const int m0  = (swz / nbn) * 256;
    const int n0  = (swz % nbn) * 256;

    const bf16_t* gA = A  + (size_t)m0 * K;
    const bf16_t* gB = Bt + (size_t)n0 * K;

    auto stage = [&](int kt) {
        bf16_t* dA = &lds[kt & 1][0][0];
        bf16_t* dB = &lds[kt & 1][1][0];
        #pragma unroll
        for (int i = 0; i < 4; ++i) {
            int q = i*512 + tid, row = q >> 3, s = q & 7;
            gload_lds16(gA + (size_t)row*K + kt*64 + ((s ^ (row & 7)) << 3), dA + q*8);
        }
        #pragma unroll
        for (int i = 0; i < 4; ++i) {
            int q = i*512 + tid, row = q >> 3, s = q & 7;
            gload_lds16(gB + (size_t)row*K + kt*64 + ((s ^ (row & 7)) << 3), dB + q*8);
        }
    };

    f32x4 acc[8][4];
    #pragma unroll
    for (int a = 0; a < 8; ++a)
        #pragma unroll
        for (int b = 0; b < 4; ++b) acc[a][b] = (f32x4){0.f, 0.f, 0.f, 0.f};

    const int NT = K >> 6;
    stage(0);
    asm volatile("s_waitcnt vmcnt(0)" ::: "memory");
    __builtin_amdgcn_s_barrier();

    for (int t = 0; t < NT; ++t) {
        const int cur = t & 1;
        if (t + 1 < NT) stage(t + 1);

        const bf16_t* lA = &lds[cur][0][0];
        const bf16_t* lB = &lds[cur][1][0];
        __builtin_amdgcn_s_setprio(1);
        #pragma unroll
        for (int ks = 0; ks < 2; ++ks) {
            bf16x8 bfr[4];
            #pragma unroll
            for (int nt = 0; nt < 4; ++nt)
                bfr[nt] = read_frag(lB, wn*64 + nt*16 + frow, ks*4 + kg);
            #pragma unroll
            for (int mt = 0; mt < 8; ++mt) {
                bf16x8 af = read_frag(lA, wm*128 + mt*16 + frow, ks*4 + kg);
                #pragma unroll
                for (int nt = 0; nt < 4; ++nt)
                    acc[mt][nt] = __builtin_amdgcn_mfma_f32_16x16x32_bf16(
                        af, bfr[nt], acc[mt][nt], 0, 0, 0);
            }
        }
        __builtin_amdgcn_s_setprio(0);

        if (t + 1 < NT) {
            asm volatile("s_waitcnt vmcnt(0)" ::: "memory");   // free: issued pre-compute
            __builtin_amdgcn_s_barrier();                      // publish + WAR fence
        }
    }

    const int ccol  = lane & 15;
    const int crow0 = (lane >> 4) * 4;
    #pragma unroll
    for (int nt = 0; nt < 4; ++nt) {
        const int col = n0 + wn*64 + nt*16 + ccol;
        float bv = 0.f;
        if constexpr (OUTF == 1) bv = bias[col];
        #pragma unroll
        for (int mt = 0; mt < 8; ++mt) {
            const int row = m0 + wm*128 + mt*16 + crow0;
            #pragma unroll
            for (int i = 0; i < 4; ++i) {
                if constexpr (OUTF == 1)
                    ((float*)Cp)[(size_t)(row + i)*N + col] = acc[mt][nt][i] + bv;
                else
                    ((bf16_t*)Cp)[(size_t)(row + i)*N + col] = (bf16_t)acc[mt][nt][i];
            }
        }
    }
}

// ---------------- launcher ----------------
extern "C" void kernel_launch(void* const* d_in, const int* in_sizes, int n_in,
                              void* d_out, int out_size, void* d_ws, size_t ws_size,
                              hipStream_t stream) {
    (void)in_sizes; (void)n_in; (void)out_size;
    const float* x    = (const float*)d_in[0];
    const float* G1   = (const float*)d_in[1];
    const float* G2   = (const float*)d_in[2];
    const float* G3   = (const float*)d_in[3];
    const float* bias = (const float*)d_in[4];
    const int* perm_raw = (const int*)d_in[5];
    const int* act_raw  = (const int*)d_in[6];
    const int* oip_raw  = (const int*)d_in[7];

    if (ws_size < WS_SMALL) return;

    char* ws = (char*)d_ws;
    int*    perm  = (int*)   (ws + OFF_PERM);
    int*    act   = (int*)   (ws + OFF_ACT);
    int*    oip   = (int*)   (ws + OFF_OIP);
    int*    op    = (int*)   (ws + OFF_OP);
    int*    ipinv = (int*)   (ws + OFF_IPINV);
    bf16_t* DhT   = (bf16_t*)(ws + OFF_DHT);
    float*  tab   = (float*) (ws + OFF_TAB);
    float*  T     = (float*) (ws + OFF_T);
    float*  Amat  = (float*) (ws + OFF_AM);
    bf16_t* WinT  = (bf16_t*)(ws + OFF_WIN);
    bf16_t* WoutT = (bf16_t*)(ws + OFF_WOUT);
    bf16_t* xb    = (bf16_t*)(ws + OFF_XB);
    bf16_t* xa    = (bf16_t*)(ws + OFF_XA_S);   // overlays dead T/Amat during main

    // ---- prep (weights) ----
    k_norm_idx<<<16, 256, 0, stream>>>(perm_raw, act_raw, oip_raw, perm, act, oip);
    k_invert  <<<16, 256, 0, stream>>>(oip, perm, op, ipinv);
    k_costab  <<<64, 256, 0, stream>>>(tab);
    k_dht     <<<64, 256, 0, stream>>>(tab, DhT);
    k_win     <<<2048, 256, 0, stream>>>(ipinv, act, tab, WinT);
    k_build_T <<<1024, 256, 0, stream>>>(G2, G3, T);
    k_build_A <<<2048, 256, 0, stream>>>(G1, T, Amat);
    k_wout_mfma<<<dim3(32, 16), 256, 0, stream>>>(Amat, DhT, op, WoutT);

    // ---- main: two M-halves; all pieces individually measured ----
    for (int h = 0; h < 2; ++h) {
        const float* xh = x + (size_t)h * MHALF * IN_F;
        float* outh = (float*)d_out + (size_t)h * MHALF * OUT_F;
        k_cvt<<<16384, 256, 0, stream>>>(xh, xb);
        // GEMM1: xa[8192][2048] = xb @ WinT^T       (32 x 8 = 256 wgs)
        gemm2s<0><<<256, 512, 0, stream>>>(xb, WinT, (void*)xa, nullptr,
                                           NACT, IN_F, NACT/256);
        // GEMM2: out[8192][4096] = xa @ WoutT^T + bias   (32 x 16 = 512 wgs)
        gemm2s<1><<<512, 512, 0, stream>>>(xa, WoutT, (void*)outh, bias,
                                           OUT_F, NACT, OUT_F/256);
    }
}